// Round 13
// baseline (2433.424 us; speedup 1.0000x reference)
//
#include <hip/hip_runtime.h>

#define T_STEPS 168
#define B_SZ 512
#define H_SZ 1024
#define IN_SZ 64
#define LAG_SZ 168
#define NWG 256
#define TPB 256

typedef __attribute__((ext_vector_type(8))) short short8;
typedef __attribute__((ext_vector_type(8))) __bf16 bf16x8;
typedef __attribute__((ext_vector_type(4))) float floatx4;

union V8u { short8 s; bf16x8 v; unsigned u[4]; };

__device__ __forceinline__ float bf2f(unsigned short u) {
    union { unsigned u; float f; } v; v.u = ((unsigned)u) << 16; return v.f;
}
__device__ __forceinline__ unsigned short f2bf(float x) {
    union { float f; unsigned u; } v; v.f = x;
    unsigned r = ((v.u >> 16) & 1u) + 0x7fffu;
    return (unsigned short)((v.u + r) >> 16);
}
__device__ __forceinline__ unsigned cvtpk(float a, float b) {
    unsigned r; asm("v_cvt_pk_bf16_f32 %0, %1, %2" : "=v"(r) : "v"(a), "v"(b)); return r;
}
__device__ __forceinline__ float lo_f(unsigned u) {
    union { unsigned x; float f; } v; v.x = u << 16; return v.f;
}
__device__ __forceinline__ float hi_f(unsigned u) {
    union { unsigned x; float f; } v; v.x = u & 0xffff0000u; return v.f;
}

#define MFB(a, b, c) __builtin_amdgcn_mfma_f32_16x16x32_bf16((a), (b), (c), 0, 0, 0)

// ============================================================================
// ws layout (need 14,066,752 B; ws >= 16.8 MB proven round 4):
//   whi   @ 0        : [64 n16][96 frags][64 lanes][8] u16 hi          (6,291,456)
//   h_hi  @ 6291456  : [2][512][1024] u16                              (2,097,152)
//   ypart @ 8388608  : [168 t][8 xcd][64 row][32 wg] u16 bf16 partials (5,505,024)
//   flg   @ 13893632 : [169 steps][8 xcd][32 wg] u32 flags             (173,056)
//   pop   @ 14066688 : [16] u32 rank counters                          (64)

__global__ void crnn_init2(const float* __restrict__ Whh,
                           unsigned short* __restrict__ whi,
                           unsigned short* __restrict__ h_hi,
                           unsigned short* __restrict__ ypart,
                           unsigned int* __restrict__ flg, unsigned int* __restrict__ pop)
{
    int tid = blockIdx.x * blockDim.x + threadIdx.x;
    int nthr = gridDim.x * blockDim.x;
    for (int c = tid; c < 64 * 96 * 64; c += nthr) {
        int lane = c & 63;
        int f = (c >> 6) % 96;
        int n16 = c / (96 * 64);
        int kk = f / 3, g = f % 3;
        int l15 = lane & 15, g4 = lane >> 4;
        int row = g * H_SZ + n16 * 16 + l15;
        int col = kk * 32 + g4 * 8;
        const float* src = Whh + (size_t)row * H_SZ + col;
        short8 sh;
        #pragma unroll
        for (int e = 0; e < 8; e++) sh[e] = (short)f2bf(src[e]);
        *(short8*)(whi + (size_t)c * 8) = sh;
    }
    for (int k = tid; k < 2 * B_SZ * H_SZ; k += nthr) h_hi[k] = 0;
    for (int k = tid; k < 168 * 8 * 64 * 32; k += nthr) ypart[k] = 0;
    for (int k = tid; k < 169 * 256; k += nthr) flg[k] = 0u;
    for (int k = tid; k < 16; k += nthr) pop[k] = 0u;
}

// 8 A-loads (h hi, 16B/lane) for k-block KB from buffer base VB. sc0 bypasses stale L1.
#define ISSUE_A(ARR, KB, VB) { \
    unsigned va_ = (VB) + (unsigned)((KB) * 512); \
    asm volatile("global_load_dwordx4 %0, %1, %2 sc0"            : "=v"(ARR[0].s) : "v"(va_), "s"(sAh)); \
    asm volatile("global_load_dwordx4 %0, %1, %2 offset:64 sc0"  : "=v"(ARR[1].s) : "v"(va_), "s"(sAh)); \
    asm volatile("global_load_dwordx4 %0, %1, %2 offset:128 sc0" : "=v"(ARR[2].s) : "v"(va_), "s"(sAh)); \
    asm volatile("global_load_dwordx4 %0, %1, %2 offset:192 sc0" : "=v"(ARR[3].s) : "v"(va_), "s"(sAh)); \
    asm volatile("global_load_dwordx4 %0, %1, %2 offset:256 sc0" : "=v"(ARR[4].s) : "v"(va_), "s"(sAh)); \
    asm volatile("global_load_dwordx4 %0, %1, %2 offset:320 sc0" : "=v"(ARR[5].s) : "v"(va_), "s"(sAh)); \
    asm volatile("global_load_dwordx4 %0, %1, %2 offset:384 sc0" : "=v"(ARR[6].s) : "v"(va_), "s"(sAh)); \
    asm volatile("global_load_dwordx4 %0, %1, %2 offset:448 sc0" : "=v"(ARR[7].s) : "v"(va_), "s"(sAh)); \
}

// Pin A values after the drain (rule-#18 protection against IR/sched hoisting).
#define KEEP8(ARR) { \
    _Pragma("unroll") \
    for (int _q = 0; _q < 8; _q++) asm volatile("" : "+v"(ARR[_q].s)); \
}

#define COMPUTE_G(ARR, KB) { \
    _Pragma("unroll") \
    for (int q = 0; q < 8; q++) { \
        const int kk = (KB) * 8 + q; \
        unsigned o_ = (unsigned)(kk * 64); \
        bf16x8 xA0 = *(const bf16x8*)((const char*)whhA + ((bb0 + o_) ^ swz)); \
        bf16x8 xA1 = *(const bf16x8*)((const char*)whhA + ((bb1 + o_) ^ swz)); \
        bf16x8 xA2 = *(const bf16x8*)((const char*)whhA + ((bb2 + o_) ^ swz)); \
        const char* pB = wfB + (size_t)kk * 3072; \
        bf16x8 h1_0 = *(const bf16x8*)(pB); \
        bf16x8 h1_1 = *(const bf16x8*)(pB + 1024); \
        bf16x8 h1_2 = *(const bf16x8*)(pB + 2048); \
        acc[0] = MFB(ARR[q].v, xA0, acc[0]); \
        acc[2] = MFB(ARR[q].v, xA1, acc[2]); \
        acc[4] = MFB(ARR[q].v, xA2, acc[4]); \
        acc[1] = MFB(ARR[q].v, h1_0, acc[1]); \
        acc[3] = MFB(ARR[q].v, h1_1, acc[3]); \
        acc[5] = MFB(ARR[q].v, h1_2, acc[5]); \
    } \
}

__launch_bounds__(TPB, 1)
__global__ void crnn_main2(
    const float* __restrict__ lag, const float* __restrict__ curr,
    const float* __restrict__ W1, const float* __restrict__ b1,
    const float* __restrict__ Wih, const float* __restrict__ b_ih,
    const float* __restrict__ Whh, const float* __restrict__ b_hh,
    const float* __restrict__ W3, const float* __restrict__ b3,
    const unsigned short* __restrict__ whi,
    unsigned short* __restrict__ h_hi, unsigned short* __restrict__ ypart,
    unsigned int* __restrict__ flg, unsigned int* __restrict__ pop,
    float* __restrict__ out)
{
    // ~121 KB LDS -> 1 WG/CU -> exactly 32 WGs per XCD under co-residency.
    __shared__ __align__(16) unsigned short whhA[48 * 1024];   // 96 KB tile-A W_hh hi, swizzled
    __shared__ __align__(16) unsigned short wihh[96 * 64];     // 12 KB W_ih hi
    __shared__ __align__(16) unsigned short wihl[96 * 64];     // 12 KB W_ih lo
    __shared__ int sh_xr[2];

    const int tid = threadIdx.x;
    if (tid == 0) {
        unsigned x;
        asm volatile("s_getreg_b32 %0, hwreg(HW_REG_XCC_ID)" : "=s"(x));
        x &= 7u;
        unsigned rk = __hip_atomic_fetch_add(&pop[x], 1u, __ATOMIC_RELAXED, __HIP_MEMORY_SCOPE_AGENT);
        sh_xr[0] = (int)x;
        sh_xr[1] = (int)(rk & 31u);
    }
    __syncthreads();
    const int xcc = sh_xr[0];
    const int r = sh_xr[1];
    const int RB = xcc * 64;       // this XCD's 64 batch rows
    const int J = r * 32;          // this WG's 32 hidden cols
    const int n16B = 2 * r + 1;    // streamed 16-col tile (cols J+16..J+31)

    const int lane = tid & 63;
    const int wv = tid >> 6;
    const int l15 = lane & 15;
    const int g4 = lane >> 4;

    // ---- stage tile-A W_hh hi (48 rows x 1024, cols J..J+15) into LDS, XOR-swizzled ----
    for (int c = tid; c < 48 * 128; c += TPB) {
        int rr = c >> 7, cc = c & 127;
        int gr = (rr >> 4) * H_SZ + J + (rr & 15);
        const float* src = Whh + (size_t)gr * H_SZ + cc * 8;
        short8 s;
        #pragma unroll
        for (int e = 0; e < 8; e++) s[e] = (short)f2bf(src[e]);
        unsigned byte = ((unsigned)(rr * 2048 + cc * 16)) ^ ((unsigned)((rr & 7) << 4));
        *(short8*)((char*)whhA + byte) = s;
    }
    // ---- stage W_ih hi+lo (96 rows x 64) ----
    for (int c = tid; c < 96 * 8; c += TPB) {
        int rr = c >> 3, cc = c & 7;
        int gr = (rr >> 5) * H_SZ + J + (rr & 31);
        const float* src = Wih + (size_t)gr * IN_SZ + cc * 8;
        short8 sh, sl;
        #pragma unroll
        for (int e = 0; e < 8; e++) {
            float v = src[e];
            unsigned short hi = f2bf(v);
            sh[e] = (short)hi;
            sl[e] = (short)f2bf(v - bf2f(hi));
        }
        unsigned byte = ((unsigned)(rr * 128 + cc * 16)) ^ ((unsigned)((rr & 7) << 4));
        *(short8*)((char*)wihh + byte) = sh;
        *(short8*)((char*)wihl + byte) = sl;
    }

    // ---- h0 = lag @ W1^T + b1; fp32 master stays in registers ----
    float hp[2][4];
    {
        const int brow = RB + wv * 16 + g4 * 4;
        #pragma unroll
        for (int j16 = 0; j16 < 2; j16++) {
            const int j = J + j16 * 16 + l15;
            float a[4];
            float bias = b1[j];
            #pragma unroll
            for (int e = 0; e < 4; e++) a[e] = bias;
            const float* w1p = W1 + (size_t)j * LAG_SZ;
            for (int k = 0; k < LAG_SZ; k += 4) {
                floatx4 w4 = *(const floatx4*)(w1p + k);
                #pragma unroll
                for (int e = 0; e < 4; e++) {
                    floatx4 l4 = *(const floatx4*)(lag + (size_t)(brow + e) * LAG_SZ + k);
                    a[e] += l4.x * w4.x + l4.y * w4.y + l4.z * w4.z + l4.w * w4.w;
                }
            }
            #pragma unroll
            for (int e = 0; e < 4; e++) {
                hp[j16][e] = a[e];
                h_hi[(size_t)(brow + e) * H_SZ + j] = f2bf(a[e]);
            }
        }
    }

    // loop-invariant gate biases + y weights for this lane's 2 cols
    float br_[2], bz_[2], bni_[2], bnh_[2];
    #pragma unroll
    for (int j16 = 0; j16 < 2; j16++) {
        int j = J + j16 * 16 + l15;
        br_[j16] = b_ih[j] + b_hh[j];
        bz_[j16] = b_ih[H_SZ + j] + b_hh[H_SZ + j];
        bni_[j16] = b_ih[2 * H_SZ + j];
        bnh_[j16] = b_hh[2 * H_SZ + j];
    }
    const float w3a = W3[J + l15];
    const float w3b = W3[J + 16 + l15];
    const float b3v = b3[0];

    // bases for the K-loop
    const unsigned short* sAh = h_hi;
    const char* wfB = (const char*)whi + (size_t)n16B * 98304 + lane * 16;  // hi, tile B
    const unsigned voffA0 = (unsigned)(((RB + wv * 16 + l15) * H_SZ + g4 * 8) * 2);

    // LDS B-fragment byte bases (tile A)
    const unsigned bb0 = (unsigned)((0 * 16 + l15) * 2048 + g4 * 16);
    const unsigned bb1 = (unsigned)((1 * 16 + l15) * 2048 + g4 * 16);
    const unsigned bb2 = (unsigned)((2 * 16 + l15) * 2048 + g4 * 16);
    const unsigned swz = (unsigned)((l15 & 7) << 4);

    // ---- skewed dependency barrier (agent atomics), busy-spin polls ----
    bool dead = false;
    auto set_flag = [&](int t1) {
        asm volatile("s_waitcnt vmcnt(0)" ::: "memory");  // h + ypart stores at L2
        __syncthreads();
        if (tid == 0)
            __hip_atomic_store(flg + (size_t)t1 * 256 + (size_t)xcc * 32 + (size_t)r, 1u,
                               __ATOMIC_RELAXED, __HIP_MEMORY_SCOPE_AGENT);
    };
    auto check = [&](int t, int kb) {
        if (dead) { __builtin_amdgcn_sched_barrier(0); return; }
        const unsigned int* fp = flg + (size_t)t * 256 + (size_t)xcc * 32
                               + (size_t)kb * 8 + (size_t)(lane & 7);
        int spins = 0;
        while (true) {
            unsigned v = __hip_atomic_load(fp, __ATOMIC_RELAXED, __HIP_MEMORY_SCOPE_AGENT);
            if (__ballot(v != 0) == ~0ull) break;
            if (++spins > 2000000) { dead = true; break; }   // fail finite+fast, don't wedge
        }
        __builtin_amdgcn_sched_barrier(0);
    };

    floatx4 acc_gi[6];
    auto compute_gi = [&](int t) {
        const float* xp = curr + (size_t)t * (B_SZ * IN_SZ)
                        + (size_t)(RB + wv * 16 + l15) * IN_SZ + g4 * 8;
        #pragma unroll
        for (int ni = 0; ni < 6; ni++) acc_gi[ni] = floatx4{0.f, 0.f, 0.f, 0.f};
        #pragma unroll
        for (int kg = 0; kg < 2; kg++) {
            floatx4 v0 = *(const floatx4*)(xp + kg * 32);
            floatx4 v1 = *(const floatx4*)(xp + kg * 32 + 4);
            V8u ah, al;
            ah.u[0] = cvtpk(v0.x, v0.y); ah.u[1] = cvtpk(v0.z, v0.w);
            ah.u[2] = cvtpk(v1.x, v1.y); ah.u[3] = cvtpk(v1.z, v1.w);
            al.u[0] = cvtpk(v0.x - lo_f(ah.u[0]), v0.y - hi_f(ah.u[0]));
            al.u[1] = cvtpk(v0.z - lo_f(ah.u[1]), v0.w - hi_f(ah.u[1]));
            al.u[2] = cvtpk(v1.x - lo_f(ah.u[2]), v1.y - hi_f(ah.u[2]));
            al.u[3] = cvtpk(v1.z - lo_f(ah.u[3]), v1.w - hi_f(ah.u[3]));
            #pragma unroll
            for (int g = 0; g < 3; g++) {
                #pragma unroll
                for (int j16 = 0; j16 < 2; j16++) {
                    int rr = g * 32 + j16 * 16 + l15;
                    unsigned byte = ((unsigned)(rr * 128 + kg * 64 + g4 * 16)) ^ ((unsigned)((rr & 7) << 4));
                    bf16x8 bh = *(const bf16x8*)((const char*)wihh + byte);
                    bf16x8 bl = *(const bf16x8*)((const char*)wihl + byte);
                    int ni = g * 2 + j16;
                    acc_gi[ni] = MFB(ah.v, bh, acc_gi[ni]);
                    acc_gi[ni] = MFB(al.v, bh, acc_gi[ni]);
                    acc_gi[ni] = MFB(ah.v, bl, acc_gi[ni]);
                }
            }
        }
    };

    set_flag(0);           // h0 slice published
    compute_gi(0);

    const int kb0 = r >> 3;   // start at own col-block (its flags land first)
    const int k0 = kb0, k1 = (kb0 + 1) & 3, k2 = (kb0 + 2) & 3, k3 = (kb0 + 3) & 3;

    V8u A0[8], A1[8];
    int cur = 0;
    // prologue: k0 poll + issue for step 0
    check(0, k0); ISSUE_A(A0, k0, voffA0);

    for (int t = 0; t < T_STEPS; t++) {
        const unsigned voffA_cur = voffA0 + (unsigned)cur * 1048576u;

        floatx4 acc[6];
        #pragma unroll
        for (int ni = 0; ni < 6; ni++) acc[ni] = floatx4{0.f, 0.f, 0.f, 0.f};

        check(t, k1); ISSUE_A(A1, k1, voffA_cur);   // check's vmcnt(0) drained A0
        KEEP8(A0);  COMPUTE_G(A0, k0);
        check(t, k2); ISSUE_A(A0, k2, voffA_cur);   // drained A1
        KEEP8(A1);  COMPUTE_G(A1, k1);
        check(t, k3); ISSUE_A(A1, k3, voffA_cur);   // drained A0(k2)
        KEEP8(A0);  COMPUTE_G(A0, k2);
        asm volatile("s_waitcnt vmcnt(0)" ::: "memory");   // drain A1(k3)
        __builtin_amdgcn_sched_barrier(0);
        KEEP8(A1);  COMPUTE_G(A1, k3);

        // ---- gates + state update (fp32 master in regs), write hi to next buffer ----
        {
            unsigned short* nh = h_hi + (size_t)(cur ^ 1) * 524288;
            const int brow = RB + wv * 16 + g4 * 4;
            #pragma unroll
            for (int j16 = 0; j16 < 2; j16++) {
                const int j = J + j16 * 16 + l15;
                #pragma unroll
                for (int e = 0; e < 4; e++) {
                    float grv = acc[0 + j16][e] + acc_gi[0 + j16][e] + br_[j16];
                    float gzv = acc[2 + j16][e] + acc_gi[2 + j16][e] + bz_[j16];
                    float ghn = acc[4 + j16][e] + bnh_[j16];
                    float gin = acc_gi[4 + j16][e] + bni_[j16];
                    float rg = 1.f / (1.f + __expf(-grv));
                    float zg = 1.f / (1.f + __expf(-gzv));
                    float nx = gin + rg * ghn;
                    float e2 = __expf(-2.f * fabsf(nx));
                    float th = copysignf((1.f - e2) / (1.f + e2), nx);
                    float hnew = (1.f - zg) * th + zg * hp[j16][e];
                    hp[j16][e] = hnew;
                    nh[(size_t)(brow + e) * H_SZ + j] = f2bf(hnew);
                }
            }
        }

        // ---- y partials (registers -> bf16 scratch); covered by set_flag's vmcnt ----
        {
            #pragma unroll
            for (int e = 0; e < 4; e++) {
                float p = w3a * hp[0][e] + w3b * hp[1][e];
                p += __shfl_xor(p, 1, 64);
                p += __shfl_xor(p, 2, 64);
                p += __shfl_xor(p, 4, 64);
                p += __shfl_xor(p, 8, 64);
                if (l15 == 0) {
                    int row = wv * 16 + g4 * 4 + e;   // row within XCD's 64
                    ypart[((size_t)(t * 8 + xcc) * 64 + row) * 32 + r] = f2bf(p);
                }
            }
        }

        set_flag(t + 1);    // publish h_{t+1} band + y_t partials

        if (t + 1 < T_STEPS) {
            compute_gi(t + 1);
            cur ^= 1;
            // tail poll+issue: k0 of next step overlaps the step boundary
            const unsigned voffA_nxt = voffA0 + (unsigned)cur * 1048576u;
            check(t + 1, k0); ISSUE_A(A0, k0, voffA_nxt);
        } else {
            cur ^= 1;
        }
    }

    // ---- wait all 32 WGs done (slot 168 = completion), then reduce y ----
    check(T_STEPS, 0); check(T_STEPS, 1); check(T_STEPS, 2); check(T_STEPS, 3);
    for (int q = tid; q < 2 * T_STEPS; q += TPB) {
        int t = q >> 1;
        int rowq = 2 * r + (q & 1);          // row within XCD
        const char* yp = (const char*)(ypart + ((size_t)(t * 8 + xcc) * 64 + rowq) * 32);
        V8u v0, v1, v2, v3;
        asm volatile("global_load_dwordx4 %0, %1, off sc0" : "=v"(v0.s) : "v"(yp));
        asm volatile("global_load_dwordx4 %0, %1, off offset:16 sc0" : "=v"(v1.s) : "v"(yp));
        asm volatile("global_load_dwordx4 %0, %1, off offset:32 sc0" : "=v"(v2.s) : "v"(yp));
        asm volatile("global_load_dwordx4 %0, %1, off offset:48 sc0" : "=v"(v3.s) : "v"(yp));
        asm volatile("s_waitcnt vmcnt(0)" ::: "memory");
        __builtin_amdgcn_sched_barrier(0);
        float s = b3v;
        #pragma unroll
        for (int e = 0; e < 8; e++) {
            s += bf2f((unsigned short)v0.s[e]) + bf2f((unsigned short)v1.s[e])
               + bf2f((unsigned short)v2.s[e]) + bf2f((unsigned short)v3.s[e]);
        }
        out[(size_t)(RB + rowq) * T_STEPS + t] = s;
    }
}

// ============================================================================

extern "C" void kernel_launch(void* const* d_in, const int* in_sizes, int n_in,
                              void* d_out, int out_size, void* d_ws, size_t ws_size,
                              hipStream_t stream) {
    const float* lag  = (const float*)d_in[0];
    const float* curr = (const float*)d_in[1];
    const float* W1   = (const float*)d_in[2];
    const float* b1   = (const float*)d_in[3];
    const float* Wih  = (const float*)d_in[4];
    const float* bih  = (const float*)d_in[5];
    const float* Whh  = (const float*)d_in[6];
    const float* bhh  = (const float*)d_in[7];
    const float* W3   = (const float*)d_in[8];
    const float* b3   = (const float*)d_in[9];
    float* out = (float*)d_out;
    char* w = (char*)d_ws;

    if (ws_size < (size_t)14066752) return;  // clean fail; ws >= 16.8 MB proven

    unsigned short* whi   = (unsigned short*)(w + 0);
    unsigned short* h_hi  = (unsigned short*)(w + 6291456);
    unsigned short* ypart = (unsigned short*)(w + 8388608);
    unsigned int*   flg   = (unsigned int*)(w + 13893632);
    unsigned int*   pop   = (unsigned int*)(w + 14066688);

    hipLaunchKernelGGL(crnn_init2, dim3(2048), dim3(256), 0, stream,
                       Whh, whi, h_hi, ypart, flg, pop);

    void* args[] = { (void*)&lag, (void*)&curr, (void*)&W1, (void*)&b1,
                     (void*)&Wih, (void*)&bih, (void*)&Whh, (void*)&bhh,
                     (void*)&W3, (void*)&b3, (void*)&whi,
                     (void*)&h_hi, (void*)&ypart, (void*)&flg, (void*)&pop, (void*)&out };
    hipError_t e = hipLaunchCooperativeKernel((void*)crnn_main2, dim3(NWG), dim3(TPB), args, 0, stream);
    if (e != hipSuccess) {
        (void)hipGetLastError();
        hipLaunchKernelGGL(crnn_main2, dim3(NWG), dim3(TPB), 0, stream,
                           lag, curr, W1, b1, Wih, bih, Whh, bhh, W3, b3,
                           whi, h_hi, ypart, flg, pop, out);
    }
}

// Round 15
// 2365.436 us; speedup vs baseline: 1.0287x; 1.0287x over previous
//
#include <hip/hip_runtime.h>

#define T_STEPS 168
#define B_SZ 512
#define H_SZ 1024
#define IN_SZ 64
#define LAG_SZ 168
#define NWG 256
#define TPB 256

typedef __attribute__((ext_vector_type(8))) short short8;
typedef __attribute__((ext_vector_type(8))) __bf16 bf16x8;
typedef __attribute__((ext_vector_type(4))) float floatx4;

union V8u { short8 s; bf16x8 v; unsigned u[4]; };

__device__ __forceinline__ float bf2f(unsigned short u) {
    union { unsigned u; float f; } v; v.u = ((unsigned)u) << 16; return v.f;
}
__device__ __forceinline__ unsigned short f2bf(float x) {
    union { float f; unsigned u; } v; v.f = x;
    unsigned r = ((v.u >> 16) & 1u) + 0x7fffu;
    return (unsigned short)((v.u + r) >> 16);
}
__device__ __forceinline__ unsigned cvtpk(float a, float b) {
    unsigned r; asm("v_cvt_pk_bf16_f32 %0, %1, %2" : "=v"(r) : "v"(a), "v"(b)); return r;
}
__device__ __forceinline__ float lo_f(unsigned u) {
    union { unsigned x; float f; } v; v.x = u << 16; return v.f;
}
__device__ __forceinline__ float hi_f(unsigned u) {
    union { unsigned x; float f; } v; v.x = u & 0xffff0000u; return v.f;
}

#define MFB(a, b, c) __builtin_amdgcn_mfma_f32_16x16x32_bf16((a), (b), (c), 0, 0, 0)

// ============================================================================
// ws layout (need 8,561,728 B; ws >= 16.8 MB proven round 4):
//   whi  @ 0        : [64 n16][96 frags(kk*3+g)][64 lanes][8] u16 hi  (6,291,456)
//   h_hi @ 6291456  : [2][512][1024] u16                               (2,097,152)
//   flg  @ 8388608  : [169 steps][8 xcd][32 wg] u32 flags              (173,056)
//   pop  @ 8561664  : [16] u32 rank counters                           (64)

__global__ void crnn_init2(const float* __restrict__ Whh,
                           unsigned short* __restrict__ whi,
                           unsigned short* __restrict__ h_hi,
                           unsigned int* __restrict__ flg, unsigned int* __restrict__ pop)
{
    int tid = blockIdx.x * blockDim.x + threadIdx.x;
    int nthr = gridDim.x * blockDim.x;
    for (int c = tid; c < 64 * 96 * 64; c += nthr) {
        int lane = c & 63;
        int f = (c >> 6) % 96;
        int n16 = c / (96 * 64);
        int kk = f / 3, g = f % 3;
        int l15 = lane & 15, g4 = lane >> 4;
        int row = g * H_SZ + n16 * 16 + l15;
        int col = kk * 32 + g4 * 8;
        const float* src = Whh + (size_t)row * H_SZ + col;
        short8 sh;
        #pragma unroll
        for (int e = 0; e < 8; e++) sh[e] = (short)f2bf(src[e]);
        *(short8*)(whi + (size_t)c * 8) = sh;
    }
    for (int k = tid; k < 2 * B_SZ * H_SZ; k += nthr) h_hi[k] = 0;
    for (int k = tid; k < 169 * 256; k += nthr) flg[k] = 0u;
    for (int k = tid; k < 16; k += nthr) pop[k] = 0u;
}

// 8 A-loads (h hi, 16B/lane) for k-block KB (kk = KB*8..KB*8+7). sc0 bypasses stale L1.
#define ISSUE_A(ARR, KB) { \
    unsigned va_ = voffA_cur + (unsigned)((KB) * 512); \
    asm volatile("global_load_dwordx4 %0, %1, %2 sc0"            : "=v"(ARR[0].s) : "v"(va_), "s"(sAh)); \
    asm volatile("global_load_dwordx4 %0, %1, %2 offset:64 sc0"  : "=v"(ARR[1].s) : "v"(va_), "s"(sAh)); \
    asm volatile("global_load_dwordx4 %0, %1, %2 offset:128 sc0" : "=v"(ARR[2].s) : "v"(va_), "s"(sAh)); \
    asm volatile("global_load_dwordx4 %0, %1, %2 offset:192 sc0" : "=v"(ARR[3].s) : "v"(va_), "s"(sAh)); \
    asm volatile("global_load_dwordx4 %0, %1, %2 offset:256 sc0" : "=v"(ARR[4].s) : "v"(va_), "s"(sAh)); \
    asm volatile("global_load_dwordx4 %0, %1, %2 offset:320 sc0" : "=v"(ARR[5].s) : "v"(va_), "s"(sAh)); \
    asm volatile("global_load_dwordx4 %0, %1, %2 offset:384 sc0" : "=v"(ARR[6].s) : "v"(va_), "s"(sAh)); \
    asm volatile("global_load_dwordx4 %0, %1, %2 offset:448 sc0" : "=v"(ARR[7].s) : "v"(va_), "s"(sAh)); \
}

// Pin A values: route them through a volatile asm AFTER the drain so neither
// IR speculation nor the machine scheduler can start MFMAs before the wait.
#define KEEP8(ARR) { \
    _Pragma("unroll") \
    for (int _q = 0; _q < 8; _q++) asm volatile("" : "+v"(ARR[_q].s)); \
}

// 8 kk of MFMA for k-block KB; B (tile-B hi) via plain C++ loads (compiler-
// managed counted waits; safe mixed with our waits: vmcnt retires in order).
#define COMPUTE_G(ARR, KB) { \
    _Pragma("unroll") \
    for (int q = 0; q < 8; q++) { \
        const int kk = (KB) * 8 + q; \
        unsigned o_ = (unsigned)(kk * 64); \
        bf16x8 xA0 = *(const bf16x8*)((const char*)whhA + ((bb0 + o_) ^ swz)); \
        bf16x8 xA1 = *(const bf16x8*)((const char*)whhA + ((bb1 + o_) ^ swz)); \
        bf16x8 xA2 = *(const bf16x8*)((const char*)whhA + ((bb2 + o_) ^ swz)); \
        const char* pB = wfB + (size_t)kk * 3072; \
        bf16x8 h1_0 = *(const bf16x8*)(pB); \
        bf16x8 h1_1 = *(const bf16x8*)(pB + 1024); \
        bf16x8 h1_2 = *(const bf16x8*)(pB + 2048); \
        acc[0] = MFB(ARR[q].v, xA0, acc[0]); \
        acc[2] = MFB(ARR[q].v, xA1, acc[2]); \
        acc[4] = MFB(ARR[q].v, xA2, acc[4]); \
        acc[1] = MFB(ARR[q].v, h1_0, acc[1]); \
        acc[3] = MFB(ARR[q].v, h1_1, acc[3]); \
        acc[5] = MFB(ARR[q].v, h1_2, acc[5]); \
    } \
}

__launch_bounds__(TPB, 1)
__global__ void crnn_main2(
    const float* __restrict__ lag, const float* __restrict__ curr,
    const float* __restrict__ W1, const float* __restrict__ b1,
    const float* __restrict__ Wih, const float* __restrict__ b_ih,
    const float* __restrict__ Whh, const float* __restrict__ b_hh,
    const float* __restrict__ W3, const float* __restrict__ b3,
    const unsigned short* __restrict__ whi,
    unsigned short* __restrict__ h_hi,
    unsigned int* __restrict__ flg, unsigned int* __restrict__ pop,
    float* __restrict__ out)
{
    // ~121 KB LDS -> 1 WG/CU -> exactly 32 WGs per XCD under co-residency.
    __shared__ __align__(16) unsigned short whhA[48 * 1024];   // 96 KB tile-A W_hh hi, swizzled
    __shared__ __align__(16) unsigned short wihh[96 * 64];     // 12 KB W_ih hi
    __shared__ __align__(16) unsigned short wihl[96 * 64];     // 12 KB W_ih lo
    __shared__ float red[4];
    __shared__ int sh_xr[2];

    const int tid = threadIdx.x;
    if (tid == 0) {
        unsigned x;
        asm volatile("s_getreg_b32 %0, hwreg(HW_REG_XCC_ID)" : "=s"(x));
        x &= 7u;
        unsigned rk = __hip_atomic_fetch_add(&pop[x], 1u, __ATOMIC_RELAXED, __HIP_MEMORY_SCOPE_AGENT);
        sh_xr[0] = (int)x;
        sh_xr[1] = (int)(rk & 31u);
    }
    __syncthreads();
    const int xcc = sh_xr[0];
    const int r = sh_xr[1];
    const int RB = xcc * 64;       // this XCD's 64 batch rows
    const int J = r * 32;          // this WG's 32 hidden cols
    const int n16B = 2 * r + 1;    // streamed 16-col tile (cols J+16..J+31)

    const int lane = tid & 63;
    const int wv = tid >> 6;
    const int l15 = lane & 15;
    const int g4 = lane >> 4;

    // ---- stage tile-A W_hh hi (48 rows x 1024, cols J..J+15) into LDS, XOR-swizzled ----
    for (int c = tid; c < 48 * 128; c += TPB) {
        int rr = c >> 7, cc = c & 127;
        int gr = (rr >> 4) * H_SZ + J + (rr & 15);
        const float* src = Whh + (size_t)gr * H_SZ + cc * 8;
        short8 s;
        #pragma unroll
        for (int e = 0; e < 8; e++) s[e] = (short)f2bf(src[e]);
        unsigned byte = ((unsigned)(rr * 2048 + cc * 16)) ^ ((unsigned)((rr & 7) << 4));
        *(short8*)((char*)whhA + byte) = s;
    }
    // ---- stage W_ih hi+lo (96 rows x 64) ----
    for (int c = tid; c < 96 * 8; c += TPB) {
        int rr = c >> 3, cc = c & 7;
        int gr = (rr >> 5) * H_SZ + J + (rr & 31);
        const float* src = Wih + (size_t)gr * IN_SZ + cc * 8;
        short8 sh, sl;
        #pragma unroll
        for (int e = 0; e < 8; e++) {
            float v = src[e];
            unsigned short hi = f2bf(v);
            sh[e] = (short)hi;
            sl[e] = (short)f2bf(v - bf2f(hi));
        }
        unsigned byte = ((unsigned)(rr * 128 + cc * 16)) ^ ((unsigned)((rr & 7) << 4));
        *(short8*)((char*)wihh + byte) = sh;
        *(short8*)((char*)wihl + byte) = sl;
    }

    // ---- h0 = lag @ W1^T + b1; fp32 master stays in registers ----
    float hp[2][4];
    {
        const int brow = RB + wv * 16 + g4 * 4;
        #pragma unroll
        for (int j16 = 0; j16 < 2; j16++) {
            const int j = J + j16 * 16 + l15;
            float a[4];
            float bias = b1[j];
            #pragma unroll
            for (int e = 0; e < 4; e++) a[e] = bias;
            const float* w1p = W1 + (size_t)j * LAG_SZ;
            for (int k = 0; k < LAG_SZ; k += 4) {
                floatx4 w4 = *(const floatx4*)(w1p + k);
                #pragma unroll
                for (int e = 0; e < 4; e++) {
                    floatx4 l4 = *(const floatx4*)(lag + (size_t)(brow + e) * LAG_SZ + k);
                    a[e] += l4.x * w4.x + l4.y * w4.y + l4.z * w4.z + l4.w * w4.w;
                }
            }
            #pragma unroll
            for (int e = 0; e < 4; e++) {
                hp[j16][e] = a[e];
                h_hi[(size_t)(brow + e) * H_SZ + j] = f2bf(a[e]);
            }
        }
    }

    // loop-invariant gate biases
    float br_[2], bz_[2], bni_[2], bnh_[2];
    #pragma unroll
    for (int j16 = 0; j16 < 2; j16++) {
        int j = J + j16 * 16 + l15;
        br_[j16] = b_ih[j] + b_hh[j];
        bz_[j16] = b_ih[H_SZ + j] + b_hh[H_SZ + j];
        bni_[j16] = b_ih[2 * H_SZ + j];
        bnh_[j16] = b_hh[2 * H_SZ + j];
    }

    // y constants: this WG produces y for rows RB+2r, RB+2r+1
    const int ycol = (tid & 127) * 8;
    const int yrow = RB + 2 * r + (tid >> 7);
    const floatx4 yw0 = *(const floatx4*)(W3 + ycol);
    const floatx4 yw1 = *(const floatx4*)(W3 + ycol + 4);
    const float b3v = b3[0];

    // bases for the K-loop
    const unsigned short* sAh = h_hi;
    const char* wfB = (const char*)whi + (size_t)n16B * 98304 + lane * 16;  // hi, tile B
    const unsigned voffA0 = (unsigned)(((RB + wv * 16 + l15) * H_SZ + g4 * 8) * 2);

    // LDS B-fragment byte bases (tile A)
    const unsigned bb0 = (unsigned)((0 * 16 + l15) * 2048 + g4 * 16);
    const unsigned bb1 = (unsigned)((1 * 16 + l15) * 2048 + g4 * 16);
    const unsigned bb2 = (unsigned)((2 * 16 + l15) * 2048 + g4 * 16);
    const unsigned swz = (unsigned)((l15 & 7) << 4);

    // ---- skewed dependency barrier (agent atomics — the ONLY proven flag
    // channel on gfx950: plain-store flags failed twice, r8/r14), busy-spin ----
    bool dead = false;
    auto set_flag = [&](int t1) {
        asm volatile("s_waitcnt vmcnt(0)" ::: "memory");
        __syncthreads();
        if (tid == 0)
            __hip_atomic_store(flg + (size_t)t1 * 256 + (size_t)xcc * 32 + (size_t)r, 1u,
                               __ATOMIC_RELAXED, __HIP_MEMORY_SCOPE_AGENT);
    };
    auto check = [&](int t, int kb) {
        if (dead) { __builtin_amdgcn_sched_barrier(0); return; }
        const unsigned int* fp = flg + (size_t)t * 256 + (size_t)xcc * 32
                               + (size_t)kb * 8 + (size_t)(lane & 7);
        int spins = 0;
        while (true) {
            unsigned v = __hip_atomic_load(fp, __ATOMIC_RELAXED, __HIP_MEMORY_SCOPE_AGENT);
            if (__ballot(v != 0) == ~0ull) break;
            if (++spins > 2000000) { dead = true; break; }   // fail finite+fast, don't wedge
        }
        __builtin_amdgcn_sched_barrier(0);
    };

    floatx4 acc_gi[6];
    auto compute_gi = [&](int t) {
        const float* xp = curr + (size_t)t * (B_SZ * IN_SZ)
                        + (size_t)(RB + wv * 16 + l15) * IN_SZ + g4 * 8;
        #pragma unroll
        for (int ni = 0; ni < 6; ni++) acc_gi[ni] = floatx4{0.f, 0.f, 0.f, 0.f};
        #pragma unroll
        for (int kg = 0; kg < 2; kg++) {
            floatx4 v0 = *(const floatx4*)(xp + kg * 32);
            floatx4 v1 = *(const floatx4*)(xp + kg * 32 + 4);
            V8u ah, al;
            ah.u[0] = cvtpk(v0.x, v0.y); ah.u[1] = cvtpk(v0.z, v0.w);
            ah.u[2] = cvtpk(v1.x, v1.y); ah.u[3] = cvtpk(v1.z, v1.w);
            al.u[0] = cvtpk(v0.x - lo_f(ah.u[0]), v0.y - hi_f(ah.u[0]));
            al.u[1] = cvtpk(v0.z - lo_f(ah.u[1]), v0.w - hi_f(ah.u[1]));
            al.u[2] = cvtpk(v1.x - lo_f(ah.u[2]), v1.y - hi_f(ah.u[2]));
            al.u[3] = cvtpk(v1.z - lo_f(ah.u[3]), v1.w - hi_f(ah.u[3]));
            #pragma unroll
            for (int g = 0; g < 3; g++) {
                #pragma unroll
                for (int j16 = 0; j16 < 2; j16++) {
                    int rr = g * 32 + j16 * 16 + l15;
                    unsigned byte = ((unsigned)(rr * 128 + kg * 64 + g4 * 16)) ^ ((unsigned)((rr & 7) << 4));
                    bf16x8 bh = *(const bf16x8*)((const char*)wihh + byte);
                    bf16x8 bl = *(const bf16x8*)((const char*)wihl + byte);
                    int ni = g * 2 + j16;
                    acc_gi[ni] = MFB(ah.v, bh, acc_gi[ni]);
                    acc_gi[ni] = MFB(al.v, bh, acc_gi[ni]);
                    acc_gi[ni] = MFB(ah.v, bl, acc_gi[ni]);
                }
            }
        }
    };

    // y-reduce from register-held h row (loaded pre-flag; no post-flag h access)
    auto y_reduce = [&](const V8u& yv, int tcol) {
        float p = 0.f;
        #pragma unroll
        for (int e = 0; e < 8; e++) {
            float w = (e < 4) ? yw0[e] : yw1[e - 4];
            p += bf2f((unsigned short)yv.s[e]) * w;
        }
        #pragma unroll
        for (int s = 32; s >= 1; s >>= 1) p += __shfl_down(p, s, 64);
        if (lane == 0) red[wv] = p;
        __syncthreads();
        if (tid == 0) {
            out[(size_t)(RB + 2 * r + 0) * T_STEPS + tcol] = red[0] + red[1] + b3v;
            out[(size_t)(RB + 2 * r + 1) * T_STEPS + tcol] = red[2] + red[3] + b3v;
        }
        __syncthreads();
    };

    set_flag(0);           // h0 slice published
    compute_gi(0);

    const int kb0 = r >> 3;   // start at own col-block (its flags land first)
    int cur = 0;
    for (int t = 0; t < T_STEPS; t++) {
        const unsigned voffA_cur = voffA0 + (unsigned)cur * 1048576u;

        floatx4 acc[6];
        #pragma unroll
        for (int ni = 0; ni < 6; ni++) acc[ni] = floatx4{0.f, 0.f, 0.f, 0.f};

        V8u A0[8], A1[8], yv;
        const int k0 = kb0, k1 = (kb0 + 1) & 3, k2 = (kb0 + 2) & 3, k3 = (kb0 + 3) & 3;

        check(t, k0); ISSUE_A(A0, k0);
        check(t, k1); ISSUE_A(A1, k1);      // check's internal wait drained A0 (in-order vmcnt)
        KEEP8(A0);  COMPUTE_G(A0, k0);
        check(t, k2); ISSUE_A(A0, k2);      // drained A1
        KEEP8(A1);  COMPUTE_G(A1, k1);
        check(t, k3); ISSUE_A(A1, k3);      // drained A0(k2)
        {   // y data for this step: h_t row yrow (flags_t all confirmed; pre-flag-of-t+1 read)
            const char* ph = (const char*)(h_hi + (size_t)cur * 524288 + (size_t)yrow * H_SZ + ycol);
            asm volatile("global_load_dwordx4 %0, %1, off sc0" : "=v"(yv.s) : "v"(ph));
        }
        KEEP8(A0);  COMPUTE_G(A0, k2);
        asm volatile("s_waitcnt vmcnt(0)" ::: "memory");   // drain A1(k3) + yv
        __builtin_amdgcn_sched_barrier(0);
        KEEP8(A1);  COMPUTE_G(A1, k3);

        // ---- gates + state update (fp32 master in regs), write hi to next buffer ----
        {
            unsigned short* nh = h_hi + (size_t)(cur ^ 1) * 524288;
            const int brow = RB + wv * 16 + g4 * 4;
            #pragma unroll
            for (int j16 = 0; j16 < 2; j16++) {
                const int j = J + j16 * 16 + l15;
                #pragma unroll
                for (int e = 0; e < 4; e++) {
                    float grv = acc[0 + j16][e] + acc_gi[0 + j16][e] + br_[j16];
                    float gzv = acc[2 + j16][e] + acc_gi[2 + j16][e] + bz_[j16];
                    float ghn = acc[4 + j16][e] + bnh_[j16];
                    float gin = acc_gi[4 + j16][e] + bni_[j16];
                    float rg = 1.f / (1.f + __expf(-grv));
                    float zg = 1.f / (1.f + __expf(-gzv));
                    float nx = gin + rg * ghn;
                    float e2 = __expf(-2.f * fabsf(nx));
                    float th = copysignf((1.f - e2) / (1.f + e2), nx);
                    float hnew = (1.f - zg) * th + zg * hp[j16][e];
                    hp[j16][e] = hnew;
                    nh[(size_t)(brow + e) * H_SZ + j] = f2bf(hnew);
                }
            }
        }

        set_flag(t + 1);                  // publish h_{t+1} slice ASAP
        if (t > 0) y_reduce(yv, t - 1);   // y_{t-1} = W3 . h_t (register data)
        if (t + 1 < T_STEPS) compute_gi(t + 1);

        cur ^= 1;
    }

    // final: y_167 = W3 . h_168 (check all blocks of flags_168, then read)
    check(T_STEPS, 0); check(T_STEPS, 1); check(T_STEPS, 2); check(T_STEPS, 3);
    {
        V8u yv;
        const char* ph = (const char*)(h_hi + (size_t)cur * 524288 + (size_t)yrow * H_SZ + ycol);
        asm volatile("global_load_dwordx4 %0, %1, off sc0" : "=v"(yv.s) : "v"(ph));
        asm volatile("s_waitcnt vmcnt(0)" ::: "memory");
        __builtin_amdgcn_sched_barrier(0);
        y_reduce(yv, T_STEPS - 1);
    }
}

// ============================================================================

extern "C" void kernel_launch(void* const* d_in, const int* in_sizes, int n_in,
                              void* d_out, int out_size, void* d_ws, size_t ws_size,
                              hipStream_t stream) {
    const float* lag  = (const float*)d_in[0];
    const float* curr = (const float*)d_in[1];
    const float* W1   = (const float*)d_in[2];
    const float* b1   = (const float*)d_in[3];
    const float* Wih  = (const float*)d_in[4];
    const float* bih  = (const float*)d_in[5];
    const float* Whh  = (const float*)d_in[6];
    const float* bhh  = (const float*)d_in[7];
    const float* W3   = (const float*)d_in[8];
    const float* b3   = (const float*)d_in[9];
    float* out = (float*)d_out;
    char* w = (char*)d_ws;

    if (ws_size < (size_t)8561728) return;  // clean fail; known ws >= 16.8 MB

    unsigned short* whi  = (unsigned short*)(w + 0);
    unsigned short* h_hi = (unsigned short*)(w + 6291456);
    unsigned int*   flg  = (unsigned int*)(w + 8388608);
    unsigned int*   pop  = (unsigned int*)(w + 8561664);

    hipLaunchKernelGGL(crnn_init2, dim3(2048), dim3(256), 0, stream,
                       Whh, whi, h_hi, flg, pop);

    void* args[] = { (void*)&lag, (void*)&curr, (void*)&W1, (void*)&b1,
                     (void*)&Wih, (void*)&bih, (void*)&Whh, (void*)&bhh,
                     (void*)&W3, (void*)&b3, (void*)&whi,
                     (void*)&h_hi, (void*)&flg, (void*)&pop, (void*)&out };
    hipError_t e = hipLaunchCooperativeKernel((void*)crnn_main2, dim3(NWG), dim3(TPB), args, 0, stream);
    if (e != hipSuccess) {
        (void)hipGetLastError();
        hipLaunchKernelGGL(crnn_main2, dim3(NWG), dim3(TPB), 0, stream,
                           lag, curr, W1, b1, Wih, bih, Whh, bhh, W3, b3,
                           whi, h_hi, flg, pop, out);
    }
}